// Round 1
// baseline (1764.515 us; speedup 1.0000x reference)
//
#include <hip/hip_runtime.h>
#include <hip/hip_bf16.h>
#include <math.h>

#define N_NODES 50000
#define N_EDGES 1600000
#define DIN 128
#define NH 4
#define D1 100
#define D2 20
#define NB 64
#define EPS_BN 1e-5f

// ---------------------------------------------------------------------------
// Generic fp32 GEMM: C[n, c] = sum_k A[n,k] * W[h(c)][k][j(c)], c = h*DOUT + j
// W laid out [HEADS][K][DOUT] contiguous. 64x64 tile, 4x4 register tile.
// ---------------------------------------------------------------------------
template <int K, int DOUT, int HEADS>
__global__ __launch_bounds__(256) void gemm_heads(const float* __restrict__ A,
                                                  const float* __restrict__ W,
                                                  float* __restrict__ C,
                                                  int nrows) {
  constexpr int NC = HEADS * DOUT;
  constexpr int TM = 64, TN = 64, TK = 16;
  __shared__ __align__(16) float As[TK][TM + 4];
  __shared__ __align__(16) float Ws[TK][TN + 4];
  const int row0 = blockIdx.x * TM;
  const int col0 = blockIdx.y * TN;
  const int tid = threadIdx.x;
  const int tx = tid & 15, ty = tid >> 4;
  float acc[4][4] = {};
  for (int k0 = 0; k0 < K; k0 += TK) {
    // A tile: 64 rows x 16 k
#pragma unroll
    for (int i = 0; i < 4; i++) {
      int r = (tid >> 4) + i * 16;
      int kk = tid & 15;
      int row = row0 + r;
      float v = 0.f;
      if (row < nrows) v = A[(size_t)row * K + k0 + kk];
      As[kk][r] = v;
    }
    // W tile: 16 k x 64 cols
#pragma unroll
    for (int i = 0; i < 4; i++) {
      int kk = (tid >> 6) + i * 4;
      int cc = tid & 63;
      int c = col0 + cc;
      float v = 0.f;
      if (c < NC) {
        int h = c / DOUT, j = c % DOUT;
        v = W[((size_t)h * K + (k0 + kk)) * DOUT + j];
      }
      Ws[kk][cc] = v;
    }
    __syncthreads();
#pragma unroll
    for (int kk = 0; kk < TK; kk++) {
      float4 a4 = *reinterpret_cast<const float4*>(&As[kk][ty * 4]);
      float4 b4 = *reinterpret_cast<const float4*>(&Ws[kk][tx * 4]);
      acc[0][0] += a4.x * b4.x; acc[0][1] += a4.x * b4.y; acc[0][2] += a4.x * b4.z; acc[0][3] += a4.x * b4.w;
      acc[1][0] += a4.y * b4.x; acc[1][1] += a4.y * b4.y; acc[1][2] += a4.y * b4.z; acc[1][3] += a4.y * b4.w;
      acc[2][0] += a4.z * b4.x; acc[2][1] += a4.z * b4.y; acc[2][2] += a4.z * b4.z; acc[2][3] += a4.z * b4.w;
      acc[3][0] += a4.w * b4.x; acc[3][1] += a4.w * b4.y; acc[3][2] += a4.w * b4.z; acc[3][3] += a4.w * b4.w;
    }
    __syncthreads();
  }
#pragma unroll
  for (int i = 0; i < 4; i++) {
    int row = row0 + ty * 4 + i;
    if (row < nrows) {
#pragma unroll
      for (int j = 0; j < 4; j++) {
        int c = col0 + tx * 4 + j;
        if (c < NC) C[(size_t)row * NC + c] = acc[i][j];
      }
    }
  }
}

// ---------------------------------------------------------------------------
// Attention scores: per (node, head) dot z-row slice with a[:D] and a[D:2D]
// ---------------------------------------------------------------------------
template <int DOUT>
__global__ void scores_kernel(const float* __restrict__ z,
                              const float* __restrict__ a,
                              float* __restrict__ ssrc,
                              float* __restrict__ sdst) {
  int t = blockIdx.x * blockDim.x + threadIdx.x;
  if (t >= N_NODES * NH) return;
  int n = t >> 2;
  int h = t & 3;
  const float4* zr = reinterpret_cast<const float4*>(z + (size_t)n * (NH * DOUT) + h * DOUT);
  const float4* as = reinterpret_cast<const float4*>(a + h * 2 * DOUT);
  const float4* ad = reinterpret_cast<const float4*>(a + h * 2 * DOUT + DOUT);
  float s1 = 0.f, s2 = 0.f;
#pragma unroll
  for (int j = 0; j < DOUT / 4; j++) {
    float4 v = zr[j], x = as[j], y = ad[j];
    s1 += v.x * x.x + v.y * x.y + v.z * x.z + v.w * x.w;
    s2 += v.x * y.x + v.y * y.y + v.z * y.z + v.w * y.w;
  }
  ssrc[h * N_NODES + n] = s1;
  sdst[h * N_NODES + n] = s2;
}

// ---------------------------------------------------------------------------
// CSR build: histogram, single-block scan, cursor copy, fill
// ---------------------------------------------------------------------------
__global__ void hist_kernel(const int* __restrict__ dst, int* __restrict__ cnt) {
  int e = blockIdx.x * blockDim.x + threadIdx.x;
  if (e < N_EDGES) atomicAdd(&cnt[dst[e]], 1);
}

__global__ void scan_kernel(const int* __restrict__ cnt, int* __restrict__ row_ptr, int n) {
  __shared__ int wsum[16];
  __shared__ int carry_s;
  int tid = threadIdx.x;
  int lane = tid & 63, w = tid >> 6;
  if (tid == 0) carry_s = 0;
  __syncthreads();
  for (int base = 0; base < n; base += 1024) {
    int i = base + tid;
    int v = (i < n) ? cnt[i] : 0;
    int orig = v;
    for (int off = 1; off < 64; off <<= 1) {
      int t = __shfl_up(v, off);
      if (lane >= off) v += t;
    }
    if (lane == 63) wsum[w] = v;
    __syncthreads();
    int wo = 0;
    for (int j = 0; j < w; j++) wo += wsum[j];
    int carry = carry_s;
    if (i < n) row_ptr[i] = carry + wo + v - orig;
    __syncthreads();
    if (tid == 1023) carry_s = carry + wo + v;
    __syncthreads();
  }
  if (tid == 0) row_ptr[n] = carry_s;
}

__global__ void copy_int_kernel(const int* __restrict__ a, int* __restrict__ b, int n) {
  int i = blockIdx.x * blockDim.x + threadIdx.x;
  if (i < n) b[i] = a[i];
}

__global__ void fill_kernel(const int* __restrict__ src, const int* __restrict__ dst,
                            int* __restrict__ cursor, int* __restrict__ csr_src) {
  int e = blockIdx.x * blockDim.x + threadIdx.x;
  if (e < N_EDGES) {
    int p = atomicAdd(&cursor[dst[e]], 1);
    csr_src[p] = src[e];
  }
}

// ---------------------------------------------------------------------------
// GAT layer 1 aggregation: one block per dst, one wave per head.
// Pass 1: segment max. Pass 2: exp/den + weighted z-gather accumulate.
// Output h1[d, h*100+j] = relu(sum(ex * z[src]) / den)
// ---------------------------------------------------------------------------
__global__ __launch_bounds__(256) void agg1_kernel(const float* __restrict__ z,
                                                   const float* __restrict__ ssrc,
                                                   const float* __restrict__ sdst,
                                                   const int* __restrict__ row_ptr,
                                                   const int* __restrict__ csr_src,
                                                   float* __restrict__ h1) {
  int d = blockIdx.x;
  int h = threadIdx.x >> 6, lane = threadIdx.x & 63;
  int beg = row_ptr[d], end = row_ptr[d + 1];
  int deg = end - beg;
  size_t obase = (size_t)d * (NH * D1) + h * D1;
  if (deg == 0) {
    h1[obase + lane] = 0.f;
    if (lane + 64 < D1) h1[obase + lane + 64] = 0.f;
    return;
  }
  float sd = sdst[h * N_NODES + d];
  float mx = -1e30f;
  for (int i = lane; i < deg; i += 64) {
    int s = csr_src[beg + i];
    float e = ssrc[h * N_NODES + s] + sd;
    e = e > 0.f ? e : 0.01f * e;
    mx = fmaxf(mx, e);
  }
#pragma unroll
  for (int off = 32; off > 0; off >>= 1) mx = fmaxf(mx, __shfl_xor(mx, off));
  float acc0 = 0.f, acc1 = 0.f, den = 0.f;
  for (int i = 0; i < deg; i++) {
    int s = csr_src[beg + i];
    float e = ssrc[h * N_NODES + s] + sd;
    e = e > 0.f ? e : 0.01f * e;
    float ex = __expf(e - mx);
    den += ex;
    const float* zr = z + (size_t)s * (NH * D1) + h * D1;
    acc0 += ex * zr[lane];
    if (lane + 64 < D1) acc1 += ex * zr[lane + 64];
  }
  float inv = 1.0f / den;
  float v0 = acc0 * inv;
  h1[obase + lane] = v0 > 0.f ? v0 : 0.f;
  if (lane + 64 < D1) {
    float v1 = acc1 * inv;
    h1[obase + lane + 64] = v1 > 0.f ? v1 : 0.f;
  }
}

// ---------------------------------------------------------------------------
// GAT layer 2 aggregation + head-mean + relu: h2[d,j] = relu(mean_h out_h[d,j])
// ---------------------------------------------------------------------------
__global__ __launch_bounds__(256) void agg2_kernel(const float* __restrict__ z,
                                                   const float* __restrict__ ssrc,
                                                   const float* __restrict__ sdst,
                                                   const int* __restrict__ row_ptr,
                                                   const int* __restrict__ csr_src,
                                                   float* __restrict__ h2) {
  __shared__ float hbuf[NH][D2];
  int d = blockIdx.x;
  int h = threadIdx.x >> 6, lane = threadIdx.x & 63;
  int beg = row_ptr[d], end = row_ptr[d + 1];
  int deg = end - beg;
  if (deg > 0) {
    float sd = sdst[h * N_NODES + d];
    float mx = -1e30f;
    for (int i = lane; i < deg; i += 64) {
      int s = csr_src[beg + i];
      float e = ssrc[h * N_NODES + s] + sd;
      e = e > 0.f ? e : 0.01f * e;
      mx = fmaxf(mx, e);
    }
#pragma unroll
    for (int off = 32; off > 0; off >>= 1) mx = fmaxf(mx, __shfl_xor(mx, off));
    float acc = 0.f, den = 0.f;
    for (int i = 0; i < deg; i++) {
      int s = csr_src[beg + i];
      float e = ssrc[h * N_NODES + s] + sd;
      e = e > 0.f ? e : 0.01f * e;
      float ex = __expf(e - mx);
      den += ex;
      if (lane < D2) acc += ex * z[(size_t)s * (NH * D2) + h * D2 + lane];
    }
    if (lane < D2) hbuf[h][lane] = acc / den;
  } else {
    if (lane < D2) hbuf[h][lane] = 0.f;
  }
  __syncthreads();
  if (threadIdx.x < D2) {
    int c = threadIdx.x;
    float m = 0.25f * (hbuf[0][c] + hbuf[1][c] + hbuf[2][c] + hbuf[3][c]);
    h2[(size_t)d * D2 + c] = m > 0.f ? m : 0.f;
  }
}

// ---------------------------------------------------------------------------
// Graph mean-pool (stage 1): wave-level pre-reduction (graph_id is sorted),
// one atomic per wave per column in the uniform case.
// ---------------------------------------------------------------------------
__global__ __launch_bounds__(256) void pool_kernel(const float* __restrict__ h2,
                                                   const int* __restrict__ gid,
                                                   float* __restrict__ hg,
                                                   int* __restrict__ gcnt) {
  int wave = threadIdx.x >> 6, lane = threadIdx.x & 63;
  int n = (blockIdx.x * 4 + wave) * 64 + lane;
  bool valid = n < N_NODES;
  int g = gid[valid ? n : (N_NODES - 1)];
  int g0 = __shfl(g, 0), g63 = __shfl(g, 63);
  unsigned long long mask = __ballot(valid);
  if (g0 == g63) {
    if (lane == 0) atomicAdd(&gcnt[g0], (int)__popcll(mask));
#pragma unroll
    for (int c = 0; c < D2; c++) {
      float v = valid ? h2[(size_t)n * D2 + c] : 0.f;
#pragma unroll
      for (int off = 32; off > 0; off >>= 1) v += __shfl_xor(v, off);
      if (lane == 0) atomicAdd(&hg[g0 * D2 + c], v);
    }
  } else if (valid) {
    atomicAdd(&gcnt[g], 1);
    for (int c = 0; c < D2; c++) atomicAdd(&hg[g * D2 + c], h2[(size_t)n * D2 + c]);
  }
}

// ---------------------------------------------------------------------------
// Readout MLP + BatchNorm + final projection in one block.
// ---------------------------------------------------------------------------
__global__ __launch_bounds__(256) void head_kernel(const float* __restrict__ hg,
                                                   const int* __restrict__ gcnt,
                                                   const float* __restrict__ Wf1,
                                                   const float* __restrict__ bf1,
                                                   const float* __restrict__ Wf2,
                                                   const float* __restrict__ bf2,
                                                   const float* __restrict__ Wf3,
                                                   const float* __restrict__ bf3,
                                                   const float* __restrict__ gamma,
                                                   const float* __restrict__ beta,
                                                   float* __restrict__ out) {
  __shared__ float X[NB][D2];
  __shared__ float T1[NB][128];
  __shared__ float T2[NB][32];
  __shared__ float scale_s[32], shift_s[32];
  int tid = threadIdx.x;
  for (int i = tid; i < NB * D2; i += 256) {
    int r = i / D2, c = i % D2;
    X[r][c] = hg[i] / (float)gcnt[r];
  }
  __syncthreads();
  for (int i = tid; i < NB * 128; i += 256) {
    int r = i >> 7, c = i & 127;
    float s = bf1[c];
#pragma unroll
    for (int k = 0; k < D2; k++) s += X[r][k] * Wf1[k * 128 + c];
    T1[r][c] = s > 0.f ? s : 0.f;
  }
  __syncthreads();
  for (int i = tid; i < NB * 32; i += 256) {
    int r = i >> 5, c = i & 31;
    float s = bf2[c];
#pragma unroll
    for (int k = 0; k < 128; k++) s += T1[r][k] * Wf2[k * 32 + c];
    T2[r][c] = s;
  }
  __syncthreads();
  if (tid < 32) {
    float mu = 0.f;
    for (int r = 0; r < NB; r++) mu += T2[r][tid];
    mu *= (1.f / NB);
    float var = 0.f;
    for (int r = 0; r < NB; r++) {
      float dv = T2[r][tid] - mu;
      var += dv * dv;
    }
    var *= (1.f / NB);
    float sc = gamma[tid] * rsqrtf(var + EPS_BN);
    scale_s[tid] = sc;
    shift_s[tid] = beta[tid] - mu * sc;
  }
  __syncthreads();
  if (tid < NB) {
    float s = bf3[0];
#pragma unroll
    for (int c = 0; c < 32; c++) {
      float y = scale_s[c] * T2[tid][c] + shift_s[c];
      y = y > 0.f ? y : 0.f;
      s += y * Wf3[c];
    }
    out[tid] = s;
  }
}

// ---------------------------------------------------------------------------

extern "C" void kernel_launch(void* const* d_in, const int* in_sizes, int n_in,
                              void* d_out, int out_size, void* d_ws, size_t ws_size,
                              hipStream_t stream) {
  const float* feat = (const float*)d_in[0];
  const int* src = (const int*)d_in[1];
  const int* dst = (const int*)d_in[2];
  const int* gid = (const int*)d_in[3];
  const float* W1 = (const float*)d_in[4];
  const float* a1 = (const float*)d_in[5];
  const float* W2 = (const float*)d_in[6];
  const float* a2 = (const float*)d_in[7];
  const float* Wf1 = (const float*)d_in[8];
  const float* bf1 = (const float*)d_in[9];
  const float* Wf2 = (const float*)d_in[10];
  const float* bf2 = (const float*)d_in[11];
  const float* Wf3 = (const float*)d_in[12];
  const float* bf3 = (const float*)d_in[13];
  const float* gamma2 = (const float*)d_in[14];
  const float* beta2 = (const float*)d_in[15];
  float* outp = (float*)d_out;

  // workspace carve (256-B aligned slots)
  char* p = (char*)d_ws;
  auto alloc = [&](size_t bytes) {
    void* q = (void*)p;
    p += (bytes + 255) & ~(size_t)255;
    return q;
  };
  float* z1 = (float*)alloc((size_t)N_NODES * NH * D1 * 4);  // reused as z2
  float* h1 = (float*)alloc((size_t)N_NODES * NH * D1 * 4);  // reused as h2
  float* ssrc = (float*)alloc((size_t)NH * N_NODES * 4);
  float* sdst = (float*)alloc((size_t)NH * N_NODES * 4);
  int* cnt = (int*)alloc((size_t)N_NODES * 4);
  int* row_ptr = (int*)alloc((size_t)(N_NODES + 1) * 4);
  int* cursor = (int*)alloc((size_t)N_NODES * 4);
  int* csr = (int*)alloc((size_t)N_EDGES * 4);
  float* hg = (float*)alloc((size_t)NB * D2 * 4);
  int* gcnt = (int*)alloc((size_t)NB * 4);
  float* z2 = z1;
  float* h2 = h1;

  const int rows64 = (N_NODES + 63) / 64;     // 782
  const int eblk = (N_EDGES + 255) / 256;     // 6250
  const int nblk = (N_NODES + 255) / 256;     // 196
  const int nhblk = (N_NODES * NH + 255) / 256;  // 782

  // CSR build (graph identical both layers)
  hipMemsetAsync(cnt, 0, (size_t)N_NODES * 4, stream);
  hist_kernel<<<eblk, 256, 0, stream>>>(dst, cnt);
  scan_kernel<<<1, 1024, 0, stream>>>(cnt, row_ptr, N_NODES);
  copy_int_kernel<<<nblk, 256, 0, stream>>>(row_ptr, cursor, N_NODES);
  fill_kernel<<<eblk, 256, 0, stream>>>(src, dst, cursor, csr);

  // Layer 1
  gemm_heads<DIN, D1, NH><<<dim3(rows64, 7), 256, 0, stream>>>(feat, W1, z1, N_NODES);
  scores_kernel<D1><<<nhblk, 256, 0, stream>>>(z1, a1, ssrc, sdst);
  agg1_kernel<<<N_NODES, 256, 0, stream>>>(z1, ssrc, sdst, row_ptr, csr, h1);

  // Layer 2
  gemm_heads<NH * D1, D2, NH><<<dim3(rows64, 2), 256, 0, stream>>>(h1, W2, z2, N_NODES);
  scores_kernel<D2><<<nhblk, 256, 0, stream>>>(z2, a2, ssrc, sdst);
  agg2_kernel<<<N_NODES, 256, 0, stream>>>(z2, ssrc, sdst, row_ptr, csr, h2);

  // Readout
  hipMemsetAsync(hg, 0, (size_t)NB * D2 * 4, stream);
  hipMemsetAsync(gcnt, 0, (size_t)NB * 4, stream);
  pool_kernel<<<nblk, 256, 0, stream>>>(h2, gid, hg, gcnt);
  head_kernel<<<1, 256, 0, stream>>>(hg, gcnt, Wf1, bf1, Wf2, bf2, Wf3, bf3,
                                     gamma2, beta2, outp);
}

// Round 2
// 1183.204 us; speedup vs baseline: 1.4913x; 1.4913x over previous
//
#include <hip/hip_runtime.h>
#include <hip/hip_bf16.h>
#include <math.h>

#define N_NODES 50000
#define N_EDGES 1600000
#define DIN 128
#define NH 4
#define D1 100
#define D2 20
#define NB 64
#define EPS_BN 1e-5f

// ---------------------------------------------------------------------------
// Generic fp32 GEMM: C[n, c] = sum_k A[n,k] * W[h(c)][k][j(c)], c = h*DOUT + j
// W laid out [HEADS][K][DOUT] contiguous. 64x64 tile, 4x4 register tile.
// ---------------------------------------------------------------------------
template <int K, int DOUT, int HEADS>
__global__ __launch_bounds__(256) void gemm_heads(const float* __restrict__ A,
                                                  const float* __restrict__ W,
                                                  float* __restrict__ C,
                                                  int nrows) {
  constexpr int NC = HEADS * DOUT;
  constexpr int TM = 64, TN = 64, TK = 16;
  __shared__ __align__(16) float As[TK][TM + 4];
  __shared__ __align__(16) float Ws[TK][TN + 4];
  const int row0 = blockIdx.x * TM;
  const int col0 = blockIdx.y * TN;
  const int tid = threadIdx.x;
  const int tx = tid & 15, ty = tid >> 4;
  float acc[4][4] = {};
  for (int k0 = 0; k0 < K; k0 += TK) {
#pragma unroll
    for (int i = 0; i < 4; i++) {
      int r = (tid >> 4) + i * 16;
      int kk = tid & 15;
      int row = row0 + r;
      float v = 0.f;
      if (row < nrows) v = A[(size_t)row * K + k0 + kk];
      As[kk][r] = v;
    }
#pragma unroll
    for (int i = 0; i < 4; i++) {
      int kk = (tid >> 6) + i * 4;
      int cc = tid & 63;
      int c = col0 + cc;
      float v = 0.f;
      if (c < NC) {
        int h = c / DOUT, j = c % DOUT;
        v = W[((size_t)h * K + (k0 + kk)) * DOUT + j];
      }
      Ws[kk][cc] = v;
    }
    __syncthreads();
#pragma unroll
    for (int kk = 0; kk < TK; kk++) {
      float4 a4 = *reinterpret_cast<const float4*>(&As[kk][ty * 4]);
      float4 b4 = *reinterpret_cast<const float4*>(&Ws[kk][tx * 4]);
      acc[0][0] += a4.x * b4.x; acc[0][1] += a4.x * b4.y; acc[0][2] += a4.x * b4.z; acc[0][3] += a4.x * b4.w;
      acc[1][0] += a4.y * b4.x; acc[1][1] += a4.y * b4.y; acc[1][2] += a4.y * b4.z; acc[1][3] += a4.y * b4.w;
      acc[2][0] += a4.z * b4.x; acc[2][1] += a4.z * b4.y; acc[2][2] += a4.z * b4.z; acc[2][3] += a4.z * b4.w;
      acc[3][0] += a4.w * b4.x; acc[3][1] += a4.w * b4.y; acc[3][2] += a4.w * b4.z; acc[3][3] += a4.w * b4.w;
    }
    __syncthreads();
  }
#pragma unroll
  for (int i = 0; i < 4; i++) {
    int row = row0 + ty * 4 + i;
    if (row < nrows) {
#pragma unroll
      for (int j = 0; j < 4; j++) {
        int c = col0 + tx * 4 + j;
        if (c < NC) C[(size_t)row * NC + c] = acc[i][j];
      }
    }
  }
}

// ---------------------------------------------------------------------------
// Attention scores: per (node, head) dot z-row slice with a[:D] and a[D:2D]
// ---------------------------------------------------------------------------
template <int DOUT>
__global__ void scores_kernel(const float* __restrict__ z,
                              const float* __restrict__ a,
                              float* __restrict__ ssrc,
                              float* __restrict__ sdst) {
  int t = blockIdx.x * blockDim.x + threadIdx.x;
  if (t >= N_NODES * NH) return;
  int n = t >> 2;
  int h = t & 3;
  const float4* zr = reinterpret_cast<const float4*>(z + (size_t)n * (NH * DOUT) + h * DOUT);
  const float4* as = reinterpret_cast<const float4*>(a + h * 2 * DOUT);
  const float4* ad = reinterpret_cast<const float4*>(a + h * 2 * DOUT + DOUT);
  float s1 = 0.f, s2 = 0.f;
#pragma unroll
  for (int j = 0; j < DOUT / 4; j++) {
    float4 v = zr[j], x = as[j], y = ad[j];
    s1 += v.x * x.x + v.y * x.y + v.z * x.z + v.w * x.w;
    s2 += v.x * y.x + v.y * y.y + v.z * y.z + v.w * y.w;
  }
  ssrc[h * N_NODES + n] = s1;
  sdst[h * N_NODES + n] = s2;
}

// ---------------------------------------------------------------------------
// CSR build: histogram, single-block scan, cursor copy, fill
// ---------------------------------------------------------------------------
__global__ void hist_kernel(const int* __restrict__ dst, int* __restrict__ cnt) {
  int e = blockIdx.x * blockDim.x + threadIdx.x;
  if (e < N_EDGES) atomicAdd(&cnt[dst[e]], 1);
}

__global__ void scan_kernel(const int* __restrict__ cnt, int* __restrict__ row_ptr, int n) {
  __shared__ int wsum[16];
  __shared__ int carry_s;
  int tid = threadIdx.x;
  int lane = tid & 63, w = tid >> 6;
  if (tid == 0) carry_s = 0;
  __syncthreads();
  for (int base = 0; base < n; base += 1024) {
    int i = base + tid;
    int v = (i < n) ? cnt[i] : 0;
    int orig = v;
    for (int off = 1; off < 64; off <<= 1) {
      int t = __shfl_up(v, off);
      if (lane >= off) v += t;
    }
    if (lane == 63) wsum[w] = v;
    __syncthreads();
    int wo = 0;
    for (int j = 0; j < w; j++) wo += wsum[j];
    int carry = carry_s;
    if (i < n) row_ptr[i] = carry + wo + v - orig;
    __syncthreads();
    if (tid == 1023) carry_s = carry + wo + v;
    __syncthreads();
  }
  if (tid == 0) row_ptr[n] = carry_s;
}

__global__ void copy_int_kernel(const int* __restrict__ a, int* __restrict__ b, int n) {
  int i = blockIdx.x * blockDim.x + threadIdx.x;
  if (i < n) b[i] = a[i];
}

__global__ void fill_kernel(const int* __restrict__ src, const int* __restrict__ dst,
                            int* __restrict__ cursor, int* __restrict__ csr_src) {
  int e = blockIdx.x * blockDim.x + threadIdx.x;
  if (e < N_EDGES) {
    int p = atomicAdd(&cursor[dst[e]], 1);
    csr_src[p] = src[e];
  }
}

// ---------------------------------------------------------------------------
// GAT layer 1 aggregation: one block per dst, one wave per head.
// Max pass, then x4-unrolled exp/den + weighted z-gather accumulate
// (8 independent z loads in flight per wave -> latency hiding).
// ---------------------------------------------------------------------------
__global__ __launch_bounds__(256) void agg1_kernel(const float* __restrict__ z,
                                                   const float* __restrict__ ssrc,
                                                   const float* __restrict__ sdst,
                                                   const int* __restrict__ row_ptr,
                                                   const int* __restrict__ csr_src,
                                                   float* __restrict__ h1) {
  int d = blockIdx.x;
  int h = threadIdx.x >> 6, lane = threadIdx.x & 63;
  int beg = row_ptr[d], end = row_ptr[d + 1];
  int deg = end - beg;
  size_t obase = (size_t)d * (NH * D1) + h * D1;
  bool hi = (lane + 64 < D1);
  if (deg == 0) {
    h1[obase + lane] = 0.f;
    if (hi) h1[obase + lane + 64] = 0.f;
    return;
  }
  const int hN = h * N_NODES;
  float sd = sdst[hN + d];
  float mx = -1e30f;
  for (int i = lane; i < deg; i += 64) {
    int s = csr_src[beg + i];
    float e = ssrc[hN + s] + sd;
    e = e > 0.f ? e : 0.01f * e;
    mx = fmaxf(mx, e);
  }
#pragma unroll
  for (int off = 32; off > 0; off >>= 1) mx = fmaxf(mx, __shfl_xor(mx, off));

  float acc0 = 0.f, acc1 = 0.f, acc2 = 0.f, acc3 = 0.f;
  float bcc0 = 0.f, bcc1 = 0.f, bcc2 = 0.f, bcc3 = 0.f;
  float den = 0.f;
  int i = 0;
  for (; i + 4 <= deg; i += 4) {
    int s0 = csr_src[beg + i + 0];
    int s1 = csr_src[beg + i + 1];
    int s2 = csr_src[beg + i + 2];
    int s3 = csr_src[beg + i + 3];
    float e0 = ssrc[hN + s0] + sd;
    float e1 = ssrc[hN + s1] + sd;
    float e2 = ssrc[hN + s2] + sd;
    float e3 = ssrc[hN + s3] + sd;
    e0 = e0 > 0.f ? e0 : 0.01f * e0;
    e1 = e1 > 0.f ? e1 : 0.01f * e1;
    e2 = e2 > 0.f ? e2 : 0.01f * e2;
    e3 = e3 > 0.f ? e3 : 0.01f * e3;
    float x0 = __expf(e0 - mx);
    float x1 = __expf(e1 - mx);
    float x2 = __expf(e2 - mx);
    float x3 = __expf(e3 - mx);
    den += (x0 + x1) + (x2 + x3);
    const float* z0 = z + (size_t)s0 * (NH * D1) + h * D1;
    const float* z1 = z + (size_t)s1 * (NH * D1) + h * D1;
    const float* z2 = z + (size_t)s2 * (NH * D1) + h * D1;
    const float* z3 = z + (size_t)s3 * (NH * D1) + h * D1;
    float v0 = z0[lane], v1 = z1[lane], v2 = z2[lane], v3 = z3[lane];
    acc0 += x0 * v0; acc1 += x1 * v1; acc2 += x2 * v2; acc3 += x3 * v3;
    if (hi) {
      float w0 = z0[lane + 64], w1 = z1[lane + 64], w2 = z2[lane + 64], w3 = z3[lane + 64];
      bcc0 += x0 * w0; bcc1 += x1 * w1; bcc2 += x2 * w2; bcc3 += x3 * w3;
    }
  }
  for (; i < deg; i++) {
    int s = csr_src[beg + i];
    float e = ssrc[hN + s] + sd;
    e = e > 0.f ? e : 0.01f * e;
    float ex = __expf(e - mx);
    den += ex;
    const float* zr = z + (size_t)s * (NH * D1) + h * D1;
    acc0 += ex * zr[lane];
    if (hi) bcc0 += ex * zr[lane + 64];
  }
  float inv = 1.0f / den;
  float v0 = ((acc0 + acc1) + (acc2 + acc3)) * inv;
  h1[obase + lane] = v0 > 0.f ? v0 : 0.f;
  if (hi) {
    float v1 = ((bcc0 + bcc1) + (bcc2 + bcc3)) * inv;
    h1[obase + lane + 64] = v1 > 0.f ? v1 : 0.f;
  }
}

// ---------------------------------------------------------------------------
// GAT layer 2 aggregation + head-mean + relu.
// Wave = head. Lanes split into 3 edge-groups x 20 cols (g=lane/20, j=lane%20),
// 2x unrolled -> 6 independent 80B gathers in flight. Cross-group combine via
// shuffles, then head-mean in LDS.
// ---------------------------------------------------------------------------
__global__ __launch_bounds__(256) void agg2_kernel(const float* __restrict__ z,
                                                   const float* __restrict__ ssrc,
                                                   const float* __restrict__ sdst,
                                                   const int* __restrict__ row_ptr,
                                                   const int* __restrict__ csr_src,
                                                   float* __restrict__ h2) {
  __shared__ float hbuf[NH][D2];
  int d = blockIdx.x;
  int h = threadIdx.x >> 6, lane = threadIdx.x & 63;
  int beg = row_ptr[d], end = row_ptr[d + 1];
  int deg = end - beg;
  int g = lane / D2;            // 0..3 (lanes 60..63 idle in main loop)
  int j = lane - g * D2;        // 0..19
  const int hN = h * N_NODES;
  if (deg > 0) {
    float sd = sdst[hN + d];
    float mx = -1e30f;
    for (int i = lane; i < deg; i += 64) {
      int s = csr_src[beg + i];
      float e = ssrc[hN + s] + sd;
      e = e > 0.f ? e : 0.01f * e;
      mx = fmaxf(mx, e);
    }
#pragma unroll
    for (int off = 32; off > 0; off >>= 1) mx = fmaxf(mx, __shfl_xor(mx, off));

    float acc = 0.f, den = 0.f;
    if (g < 3) {
      int i = g;
      for (; i + 3 < deg; i += 6) {
        int s0 = csr_src[beg + i];
        int s1 = csr_src[beg + i + 3];
        float e0 = ssrc[hN + s0] + sd;
        float e1 = ssrc[hN + s1] + sd;
        e0 = e0 > 0.f ? e0 : 0.01f * e0;
        e1 = e1 > 0.f ? e1 : 0.01f * e1;
        float x0 = __expf(e0 - mx);
        float x1 = __expf(e1 - mx);
        den += x0 + x1;
        float v0 = z[(size_t)s0 * (NH * D2) + h * D2 + j];
        float v1 = z[(size_t)s1 * (NH * D2) + h * D2 + j];
        acc += x0 * v0 + x1 * v1;
      }
      if (i < deg) {
        int s = csr_src[beg + i];
        float e = ssrc[hN + s] + sd;
        e = e > 0.f ? e : 0.01f * e;
        float ex = __expf(e - mx);
        den += ex;
        acc += ex * z[(size_t)s * (NH * D2) + h * D2 + j];
      }
    }
    // combine the 3 edge-groups: lane<20 pulls from lane+20 and lane+40
    float a1 = __shfl(acc, lane + 20);
    float a2 = __shfl(acc, lane + 40);
    float d1 = __shfl(den, lane + 20);
    float d2 = __shfl(den, lane + 40);
    if (lane < D2) hbuf[h][lane] = (acc + a1 + a2) / (den + d1 + d2);
  } else {
    if (lane < D2) hbuf[h][lane] = 0.f;
  }
  __syncthreads();
  if (threadIdx.x < D2) {
    int c = threadIdx.x;
    float m = 0.25f * (hbuf[0][c] + hbuf[1][c] + hbuf[2][c] + hbuf[3][c]);
    h2[(size_t)d * D2 + c] = m > 0.f ? m : 0.f;
  }
}

// ---------------------------------------------------------------------------
// Graph mean-pool (stage 1): wave-level pre-reduction (graph_id is sorted).
// ---------------------------------------------------------------------------
__global__ __launch_bounds__(256) void pool_kernel(const float* __restrict__ h2,
                                                   const int* __restrict__ gid,
                                                   float* __restrict__ hg,
                                                   int* __restrict__ gcnt) {
  int wave = threadIdx.x >> 6, lane = threadIdx.x & 63;
  int n = (blockIdx.x * 4 + wave) * 64 + lane;
  bool valid = n < N_NODES;
  int g = gid[valid ? n : (N_NODES - 1)];
  int g0 = __shfl(g, 0), g63 = __shfl(g, 63);
  unsigned long long mask = __ballot(valid);
  if (g0 == g63) {
    if (lane == 0) atomicAdd(&gcnt[g0], (int)__popcll(mask));
#pragma unroll
    for (int c = 0; c < D2; c++) {
      float v = valid ? h2[(size_t)n * D2 + c] : 0.f;
#pragma unroll
      for (int off = 32; off > 0; off >>= 1) v += __shfl_xor(v, off);
      if (lane == 0) atomicAdd(&hg[g0 * D2 + c], v);
    }
  } else if (valid) {
    atomicAdd(&gcnt[g], 1);
    for (int c = 0; c < D2; c++) atomicAdd(&hg[g * D2 + c], h2[(size_t)n * D2 + c]);
  }
}

// ---------------------------------------------------------------------------
// Readout MLP + BatchNorm + final projection in one block.
// ---------------------------------------------------------------------------
__global__ __launch_bounds__(256) void head_kernel(const float* __restrict__ hg,
                                                   const int* __restrict__ gcnt,
                                                   const float* __restrict__ Wf1,
                                                   const float* __restrict__ bf1,
                                                   const float* __restrict__ Wf2,
                                                   const float* __restrict__ bf2,
                                                   const float* __restrict__ Wf3,
                                                   const float* __restrict__ bf3,
                                                   const float* __restrict__ gamma,
                                                   const float* __restrict__ beta,
                                                   float* __restrict__ out) {
  __shared__ float X[NB][D2];
  __shared__ float T1[NB][128];
  __shared__ float T2[NB][32];
  __shared__ float scale_s[32], shift_s[32];
  int tid = threadIdx.x;
  for (int i = tid; i < NB * D2; i += 256) {
    int r = i / D2, c = i % D2;
    X[r][c] = hg[i] / (float)gcnt[r];
  }
  __syncthreads();
  for (int i = tid; i < NB * 128; i += 256) {
    int r = i >> 7, c = i & 127;
    float s = bf1[c];
#pragma unroll
    for (int k = 0; k < D2; k++) s += X[r][k] * Wf1[k * 128 + c];
    T1[r][c] = s > 0.f ? s : 0.f;
  }
  __syncthreads();
  for (int i = tid; i < NB * 32; i += 256) {
    int r = i >> 5, c = i & 31;
    float s = bf2[c];
#pragma unroll
    for (int k = 0; k < 128; k++) s += T1[r][k] * Wf2[k * 32 + c];
    T2[r][c] = s;
  }
  __syncthreads();
  if (tid < 32) {
    float mu = 0.f;
    for (int r = 0; r < NB; r++) mu += T2[r][tid];
    mu *= (1.f / NB);
    float var = 0.f;
    for (int r = 0; r < NB; r++) {
      float dv = T2[r][tid] - mu;
      var += dv * dv;
    }
    var *= (1.f / NB);
    float sc = gamma[tid] * rsqrtf(var + EPS_BN);
    scale_s[tid] = sc;
    shift_s[tid] = beta[tid] - mu * sc;
  }
  __syncthreads();
  if (tid < NB) {
    float s = bf3[0];
#pragma unroll
    for (int c = 0; c < 32; c++) {
      float y = scale_s[c] * T2[tid][c] + shift_s[c];
      y = y > 0.f ? y : 0.f;
      s += y * Wf3[c];
    }
    out[tid] = s;
  }
}

// ---------------------------------------------------------------------------

extern "C" void kernel_launch(void* const* d_in, const int* in_sizes, int n_in,
                              void* d_out, int out_size, void* d_ws, size_t ws_size,
                              hipStream_t stream) {
  const float* feat = (const float*)d_in[0];
  const int* src = (const int*)d_in[1];
  const int* dst = (const int*)d_in[2];
  const int* gid = (const int*)d_in[3];
  const float* W1 = (const float*)d_in[4];
  const float* a1 = (const float*)d_in[5];
  const float* W2 = (const float*)d_in[6];
  const float* a2 = (const float*)d_in[7];
  const float* Wf1 = (const float*)d_in[8];
  const float* bf1 = (const float*)d_in[9];
  const float* Wf2 = (const float*)d_in[10];
  const float* bf2 = (const float*)d_in[11];
  const float* Wf3 = (const float*)d_in[12];
  const float* bf3 = (const float*)d_in[13];
  const float* gamma2 = (const float*)d_in[14];
  const float* beta2 = (const float*)d_in[15];
  float* outp = (float*)d_out;

  char* p = (char*)d_ws;
  auto alloc = [&](size_t bytes) {
    void* q = (void*)p;
    p += (bytes + 255) & ~(size_t)255;
    return q;
  };
  float* z1 = (float*)alloc((size_t)N_NODES * NH * D1 * 4);  // reused as z2
  float* h1 = (float*)alloc((size_t)N_NODES * NH * D1 * 4);  // reused as h2
  float* ssrc = (float*)alloc((size_t)NH * N_NODES * 4);
  float* sdst = (float*)alloc((size_t)NH * N_NODES * 4);
  int* cnt = (int*)alloc((size_t)N_NODES * 4);
  int* row_ptr = (int*)alloc((size_t)(N_NODES + 1) * 4);
  int* cursor = (int*)alloc((size_t)N_NODES * 4);
  int* csr = (int*)alloc((size_t)N_EDGES * 4);
  float* hg = (float*)alloc((size_t)NB * D2 * 4);
  int* gcnt = (int*)alloc((size_t)NB * 4);
  float* z2 = z1;
  float* h2 = h1;

  const int rows64 = (N_NODES + 63) / 64;        // 782
  const int eblk = (N_EDGES + 255) / 256;        // 6250
  const int nblk = (N_NODES + 255) / 256;        // 196
  const int nhblk = (N_NODES * NH + 255) / 256;  // 782

  // CSR build (graph identical both layers)
  hipMemsetAsync(cnt, 0, (size_t)N_NODES * 4, stream);
  hist_kernel<<<eblk, 256, 0, stream>>>(dst, cnt);
  scan_kernel<<<1, 1024, 0, stream>>>(cnt, row_ptr, N_NODES);
  copy_int_kernel<<<nblk, 256, 0, stream>>>(row_ptr, cursor, N_NODES);
  fill_kernel<<<eblk, 256, 0, stream>>>(src, dst, cursor, csr);

  // Layer 1
  gemm_heads<DIN, D1, NH><<<dim3(rows64, 7), 256, 0, stream>>>(feat, W1, z1, N_NODES);
  scores_kernel<D1><<<nhblk, 256, 0, stream>>>(z1, a1, ssrc, sdst);
  agg1_kernel<<<N_NODES, 256, 0, stream>>>(z1, ssrc, sdst, row_ptr, csr, h1);

  // Layer 2
  gemm_heads<NH * D1, D2, NH><<<dim3(rows64, 2), 256, 0, stream>>>(h1, W2, z2, N_NODES);
  scores_kernel<D2><<<nhblk, 256, 0, stream>>>(z2, a2, ssrc, sdst);
  agg2_kernel<<<N_NODES, 256, 0, stream>>>(z2, ssrc, sdst, row_ptr, csr, h2);

  // Readout
  hipMemsetAsync(hg, 0, (size_t)NB * D2 * 4, stream);
  hipMemsetAsync(gcnt, 0, (size_t)NB * 4, stream);
  pool_kernel<<<nblk, 256, 0, stream>>>(h2, gid, hg, gcnt);
  head_kernel<<<1, 256, 0, stream>>>(hg, gcnt, Wf1, bf1, Wf2, bf2, Wf3, bf3,
                                     gamma2, beta2, outp);
}

// Round 3
// 989.864 us; speedup vs baseline: 1.7826x; 1.1953x over previous
//
#include <hip/hip_runtime.h>
#include <hip/hip_bf16.h>
#include <math.h>

#define N_NODES 50000
#define N_EDGES 1600000
#define DIN 128
#define NH 4
#define D1 100
#define P1 128   // padded per-head width for z1 (bf16)
#define D2 20
#define P2 32    // padded per-head width for z2 (bf16)
#define NB 64
#define EPS_BN 1e-5f

typedef unsigned int uint;
typedef unsigned short ushort;

__device__ __forceinline__ void bf16x2_unpack(uint p, float& lo, float& hi) {
  lo = __uint_as_float(p << 16);
  hi = __uint_as_float(p & 0xffff0000u);
}

// ---------------------------------------------------------------------------
// fp32 GEMM -> bf16 head-padded output.
// C[n][h*PAD + j] = sum_k A[n,k] * W[h][k][j], head h = c/DOUT, j = c%DOUT
// ---------------------------------------------------------------------------
template <int K, int DOUT, int HEADS, int PAD>
__global__ __launch_bounds__(256) void gemm_heads_bf16(const float* __restrict__ A,
                                                       const float* __restrict__ W,
                                                       __hip_bfloat16* __restrict__ C,
                                                       int nrows) {
  constexpr int NC = HEADS * DOUT;
  constexpr int TM = 64, TN = 64, TK = 16;
  __shared__ __align__(16) float As[TK][TM + 4];
  __shared__ __align__(16) float Ws[TK][TN + 4];
  const int row0 = blockIdx.x * TM;
  const int col0 = blockIdx.y * TN;
  const int tid = threadIdx.x;
  const int tx = tid & 15, ty = tid >> 4;
  float acc[4][4] = {};
  for (int k0 = 0; k0 < K; k0 += TK) {
#pragma unroll
    for (int i = 0; i < 4; i++) {
      int r = (tid >> 4) + i * 16;
      int kk = tid & 15;
      int row = row0 + r;
      float v = 0.f;
      if (row < nrows) v = A[(size_t)row * K + k0 + kk];
      As[kk][r] = v;
    }
#pragma unroll
    for (int i = 0; i < 4; i++) {
      int kk = (tid >> 6) + i * 4;
      int cc = tid & 63;
      int c = col0 + cc;
      float v = 0.f;
      if (c < NC) {
        int h = c / DOUT, j = c % DOUT;
        v = W[((size_t)h * K + (k0 + kk)) * DOUT + j];
      }
      Ws[kk][cc] = v;
    }
    __syncthreads();
#pragma unroll
    for (int kk = 0; kk < TK; kk++) {
      float4 a4 = *reinterpret_cast<const float4*>(&As[kk][ty * 4]);
      float4 b4 = *reinterpret_cast<const float4*>(&Ws[kk][tx * 4]);
      acc[0][0] += a4.x * b4.x; acc[0][1] += a4.x * b4.y; acc[0][2] += a4.x * b4.z; acc[0][3] += a4.x * b4.w;
      acc[1][0] += a4.y * b4.x; acc[1][1] += a4.y * b4.y; acc[1][2] += a4.y * b4.z; acc[1][3] += a4.y * b4.w;
      acc[2][0] += a4.z * b4.x; acc[2][1] += a4.z * b4.y; acc[2][2] += a4.z * b4.z; acc[2][3] += a4.z * b4.w;
      acc[3][0] += a4.w * b4.x; acc[3][1] += a4.w * b4.y; acc[3][2] += a4.w * b4.z; acc[3][3] += a4.w * b4.w;
    }
    __syncthreads();
  }
#pragma unroll
  for (int i = 0; i < 4; i++) {
    int row = row0 + ty * 4 + i;
    if (row < nrows) {
#pragma unroll
      for (int j = 0; j < 4; j++) {
        int c = col0 + tx * 4 + j;
        if (c < NC) {
          int h = c / DOUT, cj = c % DOUT;
          C[(size_t)row * (HEADS * PAD) + h * PAD + cj] = __float2bfloat16(acc[i][j]);
        }
      }
    }
  }
}

// ---------------------------------------------------------------------------
// Attention scores from bf16 packed z. One thread per (node, head).
// ---------------------------------------------------------------------------
template <int DOUT, int PAD>
__global__ void scores_kernel(const __hip_bfloat16* __restrict__ z,
                              const float* __restrict__ a,
                              float* __restrict__ ssrc,
                              float* __restrict__ sdst) {
  int t = blockIdx.x * blockDim.x + threadIdx.x;
  if (t >= N_NODES * NH) return;
  int n = t >> 2;
  int h = t & 3;
  const uint* zr = reinterpret_cast<const uint*>(z) + (size_t)n * (NH * PAD / 2) + h * (PAD / 2);
  const float* as = a + h * 2 * DOUT;
  const float* ad = as + DOUT;
  float s1 = 0.f, s2 = 0.f;
  for (int j = 0; j < DOUT / 2; j++) {
    float lo, hi;
    bf16x2_unpack(zr[j], lo, hi);
    s1 += lo * as[2 * j] + hi * as[2 * j + 1];
    s2 += lo * ad[2 * j] + hi * ad[2 * j + 1];
  }
  ssrc[h * N_NODES + n] = s1;
  sdst[h * N_NODES + n] = s2;
}

// ---------------------------------------------------------------------------
// CSR build: histogram, single-block scan, cursor copy, fill
// ---------------------------------------------------------------------------
__global__ void hist_kernel(const int* __restrict__ dst, int* __restrict__ cnt) {
  int e = blockIdx.x * blockDim.x + threadIdx.x;
  if (e < N_EDGES) atomicAdd(&cnt[dst[e]], 1);
}

__global__ void scan_kernel(const int* __restrict__ cnt, int* __restrict__ row_ptr, int n) {
  __shared__ int wsum[16];
  __shared__ int carry_s;
  int tid = threadIdx.x;
  int lane = tid & 63, w = tid >> 6;
  if (tid == 0) carry_s = 0;
  __syncthreads();
  for (int base = 0; base < n; base += 1024) {
    int i = base + tid;
    int v = (i < n) ? cnt[i] : 0;
    int orig = v;
    for (int off = 1; off < 64; off <<= 1) {
      int t = __shfl_up(v, off);
      if (lane >= off) v += t;
    }
    if (lane == 63) wsum[w] = v;
    __syncthreads();
    int wo = 0;
    for (int j = 0; j < w; j++) wo += wsum[j];
    int carry = carry_s;
    if (i < n) row_ptr[i] = carry + wo + v - orig;
    __syncthreads();
    if (tid == 1023) carry_s = carry + wo + v;
    __syncthreads();
  }
  if (tid == 0) row_ptr[n] = carry_s;
}

__global__ void copy_int_kernel(const int* __restrict__ a, int* __restrict__ b, int n) {
  int i = blockIdx.x * blockDim.x + threadIdx.x;
  if (i < n) b[i] = a[i];
}

__global__ void fill_kernel(const int* __restrict__ src, const int* __restrict__ dst,
                            int* __restrict__ cursor, int* __restrict__ csr_src) {
  int e = blockIdx.x * blockDim.x + threadIdx.x;
  if (e < N_EDGES) {
    int p = atomicAdd(&cursor[dst[e]], 1);
    csr_src[p] = src[e];
  }
}

// ---------------------------------------------------------------------------
// GAT layer 1 aggregation. Block = dst, wave = head. Lanes 0..49 each own a
// packed column pair (2j, 2j+1). Unroll 8 -> 8 independent 200B gathers.
// ---------------------------------------------------------------------------
__global__ __launch_bounds__(256) void agg1_kernel(const __hip_bfloat16* __restrict__ z,
                                                   const float* __restrict__ ssrc,
                                                   const float* __restrict__ sdst,
                                                   const int* __restrict__ row_ptr,
                                                   const int* __restrict__ csr_src,
                                                   float* __restrict__ h1) {
  int d = blockIdx.x;
  int h = threadIdx.x >> 6, lane = threadIdx.x & 63;
  int beg = row_ptr[d], end = row_ptr[d + 1];
  int deg = end - beg;
  size_t obase = (size_t)d * (NH * D1) + h * D1;
  bool act = lane < D1 / 2;  // 50 lanes
  if (deg == 0) {
    if (act) *reinterpret_cast<float2*>(h1 + obase + 2 * lane) = make_float2(0.f, 0.f);
    return;
  }
  const int hN = h * N_NODES;
  float sd = sdst[hN + d];
  float mx = -1e30f;
  for (int i = lane; i < deg; i += 64) {
    int s = csr_src[beg + i];
    float e = ssrc[hN + s] + sd;
    e = e > 0.f ? e : 0.01f * e;
    mx = fmaxf(mx, e);
  }
#pragma unroll
  for (int off = 32; off > 0; off >>= 1) mx = fmaxf(mx, __shfl_xor(mx, off));

  if (!act) return;
  const uint* zb = reinterpret_cast<const uint*>(z);
  const int hco = h * (P1 / 2) + lane;  // uint offset within row
  float aE0 = 0.f, aE1 = 0.f, aE2 = 0.f, aE3 = 0.f;
  float aO0 = 0.f, aO1 = 0.f, aO2 = 0.f, aO3 = 0.f;
  float den = 0.f;
  int i = 0;
  for (; i + 8 <= deg; i += 8) {
    int s0 = csr_src[beg + i + 0], s1 = csr_src[beg + i + 1];
    int s2 = csr_src[beg + i + 2], s3 = csr_src[beg + i + 3];
    int s4 = csr_src[beg + i + 4], s5 = csr_src[beg + i + 5];
    int s6 = csr_src[beg + i + 6], s7 = csr_src[beg + i + 7];
    float e0 = ssrc[hN + s0] + sd, e1 = ssrc[hN + s1] + sd;
    float e2 = ssrc[hN + s2] + sd, e3 = ssrc[hN + s3] + sd;
    float e4 = ssrc[hN + s4] + sd, e5 = ssrc[hN + s5] + sd;
    float e6 = ssrc[hN + s6] + sd, e7 = ssrc[hN + s7] + sd;
    e0 = e0 > 0.f ? e0 : 0.01f * e0; e1 = e1 > 0.f ? e1 : 0.01f * e1;
    e2 = e2 > 0.f ? e2 : 0.01f * e2; e3 = e3 > 0.f ? e3 : 0.01f * e3;
    e4 = e4 > 0.f ? e4 : 0.01f * e4; e5 = e5 > 0.f ? e5 : 0.01f * e5;
    e6 = e6 > 0.f ? e6 : 0.01f * e6; e7 = e7 > 0.f ? e7 : 0.01f * e7;
    float x0 = __expf(e0 - mx), x1 = __expf(e1 - mx);
    float x2 = __expf(e2 - mx), x3 = __expf(e3 - mx);
    float x4 = __expf(e4 - mx), x5 = __expf(e5 - mx);
    float x6 = __expf(e6 - mx), x7 = __expf(e7 - mx);
    den += ((x0 + x1) + (x2 + x3)) + ((x4 + x5) + (x6 + x7));
    uint p0 = zb[(size_t)s0 * (NH * P1 / 2) + hco];
    uint p1 = zb[(size_t)s1 * (NH * P1 / 2) + hco];
    uint p2 = zb[(size_t)s2 * (NH * P1 / 2) + hco];
    uint p3 = zb[(size_t)s3 * (NH * P1 / 2) + hco];
    uint p4 = zb[(size_t)s4 * (NH * P1 / 2) + hco];
    uint p5 = zb[(size_t)s5 * (NH * P1 / 2) + hco];
    uint p6 = zb[(size_t)s6 * (NH * P1 / 2) + hco];
    uint p7 = zb[(size_t)s7 * (NH * P1 / 2) + hco];
    float lo, hi;
    bf16x2_unpack(p0, lo, hi); aE0 += x0 * lo; aO0 += x0 * hi;
    bf16x2_unpack(p1, lo, hi); aE1 += x1 * lo; aO1 += x1 * hi;
    bf16x2_unpack(p2, lo, hi); aE2 += x2 * lo; aO2 += x2 * hi;
    bf16x2_unpack(p3, lo, hi); aE3 += x3 * lo; aO3 += x3 * hi;
    bf16x2_unpack(p4, lo, hi); aE0 += x4 * lo; aO0 += x4 * hi;
    bf16x2_unpack(p5, lo, hi); aE1 += x5 * lo; aO1 += x5 * hi;
    bf16x2_unpack(p6, lo, hi); aE2 += x6 * lo; aO2 += x6 * hi;
    bf16x2_unpack(p7, lo, hi); aE3 += x7 * lo; aO3 += x7 * hi;
  }
  for (; i < deg; i++) {
    int s = csr_src[beg + i];
    float e = ssrc[hN + s] + sd;
    e = e > 0.f ? e : 0.01f * e;
    float ex = __expf(e - mx);
    den += ex;
    uint p = zb[(size_t)s * (NH * P1 / 2) + hco];
    float lo, hi;
    bf16x2_unpack(p, lo, hi);
    aE0 += ex * lo; aO0 += ex * hi;
  }
  float inv = 1.0f / den;
  float vE = ((aE0 + aE1) + (aE2 + aE3)) * inv;
  float vO = ((aO0 + aO1) + (aO2 + aO3)) * inv;
  float2 o;
  o.x = vE > 0.f ? vE : 0.f;
  o.y = vO > 0.f ? vO : 0.f;
  *reinterpret_cast<float2*>(h1 + obase + 2 * lane) = o;
}

// ---------------------------------------------------------------------------
// GAT layer 2 aggregation + head-mean + relu. Wave = head.
// 6 edge-groups x 10 lanes (col pair each), 2x unroll -> 12 gathers in flight.
// ---------------------------------------------------------------------------
__global__ __launch_bounds__(256) void agg2_kernel(const __hip_bfloat16* __restrict__ z,
                                                   const float* __restrict__ ssrc,
                                                   const float* __restrict__ sdst,
                                                   const int* __restrict__ row_ptr,
                                                   const int* __restrict__ csr_src,
                                                   float* __restrict__ h2) {
  __shared__ float hbuf[NH][D2];
  int d = blockIdx.x;
  int h = threadIdx.x >> 6, lane = threadIdx.x & 63;
  int beg = row_ptr[d], end = row_ptr[d + 1];
  int deg = end - beg;
  int g = lane / 10;         // 0..5 active, 6 idle
  int j = lane - g * 10;     // 0..9 -> cols 2j, 2j+1
  const int hN = h * N_NODES;
  if (deg > 0) {
    float sd = sdst[hN + d];
    float mx = -1e30f;
    for (int i = lane; i < deg; i += 64) {
      int s = csr_src[beg + i];
      float e = ssrc[hN + s] + sd;
      e = e > 0.f ? e : 0.01f * e;
      mx = fmaxf(mx, e);
    }
#pragma unroll
    for (int off = 32; off > 0; off >>= 1) mx = fmaxf(mx, __shfl_xor(mx, off));

    const uint* zb = reinterpret_cast<const uint*>(z);
    const int hco = h * (P2 / 2) + j;
    float aE = 0.f, aO = 0.f, den = 0.f;
    if (g < 6) {
      int i = g;
      for (; i + 6 < deg; i += 12) {
        int s0 = csr_src[beg + i];
        int s1 = csr_src[beg + i + 6];
        float e0 = ssrc[hN + s0] + sd;
        float e1 = ssrc[hN + s1] + sd;
        e0 = e0 > 0.f ? e0 : 0.01f * e0;
        e1 = e1 > 0.f ? e1 : 0.01f * e1;
        float x0 = __expf(e0 - mx);
        float x1 = __expf(e1 - mx);
        den += x0 + x1;
        uint p0 = zb[(size_t)s0 * (NH * P2 / 2) + hco];
        uint p1 = zb[(size_t)s1 * (NH * P2 / 2) + hco];
        float lo, hi;
        bf16x2_unpack(p0, lo, hi); aE += x0 * lo; aO += x0 * hi;
        bf16x2_unpack(p1, lo, hi); aE += x1 * lo; aO += x1 * hi;
      }
      if (i < deg) {
        int s = csr_src[beg + i];
        float e = ssrc[hN + s] + sd;
        e = e > 0.f ? e : 0.01f * e;
        float ex = __expf(e - mx);
        den += ex;
        uint p = zb[(size_t)s * (NH * P2 / 2) + hco];
        float lo, hi;
        bf16x2_unpack(p, lo, hi);
        aE += ex * lo; aO += ex * hi;
      }
    }
    // combine the 6 edge-groups: lane<10 pulls from lanes +10k
    float tE = aE, tO = aO, tD = den;
#pragma unroll
    for (int k = 1; k < 6; k++) {
      tE += __shfl(aE, lane + 10 * k);
      tO += __shfl(aO, lane + 10 * k);
      tD += __shfl(den, lane + 10 * k);
    }
    if (lane < 10) {
      float invd = 1.0f / tD;
      hbuf[h][2 * j] = tE * invd;
      hbuf[h][2 * j + 1] = tO * invd;
    }
  } else {
    if (lane < 10) {
      hbuf[h][2 * j] = 0.f;
      hbuf[h][2 * j + 1] = 0.f;
    }
  }
  __syncthreads();
  if (threadIdx.x < D2) {
    int c = threadIdx.x;
    float m = 0.25f * (hbuf[0][c] + hbuf[1][c] + hbuf[2][c] + hbuf[3][c]);
    h2[(size_t)d * D2 + c] = m > 0.f ? m : 0.f;
  }
}

// ---------------------------------------------------------------------------
// Graph mean-pool (stage 1): wave-level pre-reduction (graph_id is sorted).
// ---------------------------------------------------------------------------
__global__ __launch_bounds__(256) void pool_kernel(const float* __restrict__ h2,
                                                   const int* __restrict__ gid,
                                                   float* __restrict__ hg,
                                                   int* __restrict__ gcnt) {
  int wave = threadIdx.x >> 6, lane = threadIdx.x & 63;
  int n = (blockIdx.x * 4 + wave) * 64 + lane;
  bool valid = n < N_NODES;
  int g = gid[valid ? n : (N_NODES - 1)];
  int g0 = __shfl(g, 0), g63 = __shfl(g, 63);
  unsigned long long mask = __ballot(valid);
  if (g0 == g63) {
    if (lane == 0) atomicAdd(&gcnt[g0], (int)__popcll(mask));
#pragma unroll
    for (int c = 0; c < D2; c++) {
      float v = valid ? h2[(size_t)n * D2 + c] : 0.f;
#pragma unroll
      for (int off = 32; off > 0; off >>= 1) v += __shfl_xor(v, off);
      if (lane == 0) atomicAdd(&hg[g0 * D2 + c], v);
    }
  } else if (valid) {
    atomicAdd(&gcnt[g], 1);
    for (int c = 0; c < D2; c++) atomicAdd(&hg[g * D2 + c], h2[(size_t)n * D2 + c]);
  }
}

// ---------------------------------------------------------------------------
// Readout MLP + BatchNorm + final projection in one block.
// ---------------------------------------------------------------------------
__global__ __launch_bounds__(256) void head_kernel(const float* __restrict__ hg,
                                                   const int* __restrict__ gcnt,
                                                   const float* __restrict__ Wf1,
                                                   const float* __restrict__ bf1,
                                                   const float* __restrict__ Wf2,
                                                   const float* __restrict__ bf2,
                                                   const float* __restrict__ Wf3,
                                                   const float* __restrict__ bf3,
                                                   const float* __restrict__ gamma,
                                                   const float* __restrict__ beta,
                                                   float* __restrict__ out) {
  __shared__ float X[NB][D2];
  __shared__ float T1[NB][128];
  __shared__ float T2[NB][32];
  __shared__ float scale_s[32], shift_s[32];
  int tid = threadIdx.x;
  for (int i = tid; i < NB * D2; i += 256) {
    int r = i / D2, c = i % D2;
    X[r][c] = hg[i] / (float)gcnt[r];
  }
  __syncthreads();
  for (int i = tid; i < NB * 128; i += 256) {
    int r = i >> 7, c = i & 127;
    float s = bf1[c];
#pragma unroll
    for (int k = 0; k < D2; k++) s += X[r][k] * Wf1[k * 128 + c];
    T1[r][c] = s > 0.f ? s : 0.f;
  }
  __syncthreads();
  for (int i = tid; i < NB * 32; i += 256) {
    int r = i >> 5, c = i & 31;
    float s = bf2[c];
#pragma unroll
    for (int k = 0; k < 128; k++) s += T1[r][k] * Wf2[k * 32 + c];
    T2[r][c] = s;
  }
  __syncthreads();
  if (tid < 32) {
    float mu = 0.f;
    for (int r = 0; r < NB; r++) mu += T2[r][tid];
    mu *= (1.f / NB);
    float var = 0.f;
    for (int r = 0; r < NB; r++) {
      float dv = T2[r][tid] - mu;
      var += dv * dv;
    }
    var *= (1.f / NB);
    float sc = gamma[tid] * rsqrtf(var + EPS_BN);
    scale_s[tid] = sc;
    shift_s[tid] = beta[tid] - mu * sc;
  }
  __syncthreads();
  if (tid < NB) {
    float s = bf3[0];
#pragma unroll
    for (int c = 0; c < 32; c++) {
      float y = scale_s[c] * T2[tid][c] + shift_s[c];
      y = y > 0.f ? y : 0.f;
      s += y * Wf3[c];
    }
    out[tid] = s;
  }
}

// ---------------------------------------------------------------------------

extern "C" void kernel_launch(void* const* d_in, const int* in_sizes, int n_in,
                              void* d_out, int out_size, void* d_ws, size_t ws_size,
                              hipStream_t stream) {
  const float* feat = (const float*)d_in[0];
  const int* src = (const int*)d_in[1];
  const int* dst = (const int*)d_in[2];
  const int* gid = (const int*)d_in[3];
  const float* W1 = (const float*)d_in[4];
  const float* a1 = (const float*)d_in[5];
  const float* W2 = (const float*)d_in[6];
  const float* a2 = (const float*)d_in[7];
  const float* Wf1 = (const float*)d_in[8];
  const float* bf1 = (const float*)d_in[9];
  const float* Wf2 = (const float*)d_in[10];
  const float* bf2 = (const float*)d_in[11];
  const float* Wf3 = (const float*)d_in[12];
  const float* bf3 = (const float*)d_in[13];
  const float* gamma2 = (const float*)d_in[14];
  const float* beta2 = (const float*)d_in[15];
  float* outp = (float*)d_out;

  char* p = (char*)d_ws;
  auto alloc = [&](size_t bytes) {
    void* q = (void*)p;
    p += (bytes + 255) & ~(size_t)255;
    return q;
  };
  __hip_bfloat16* z1b = (__hip_bfloat16*)alloc((size_t)N_NODES * NH * P1 * 2);  // 51.2 MB
  __hip_bfloat16* z2b = (__hip_bfloat16*)alloc((size_t)N_NODES * NH * P2 * 2);  // 12.8 MB
  float* h1 = (float*)alloc((size_t)N_NODES * NH * D1 * 4);                      // 80 MB
  float* ssrc = (float*)alloc((size_t)NH * N_NODES * 4);
  float* sdst = (float*)alloc((size_t)NH * N_NODES * 4);
  int* cnt = (int*)alloc((size_t)N_NODES * 4);
  int* row_ptr = (int*)alloc((size_t)(N_NODES + 1) * 4);
  int* cursor = (int*)alloc((size_t)N_NODES * 4);
  int* csr = (int*)alloc((size_t)N_EDGES * 4);
  float* hg = (float*)alloc((size_t)NB * D2 * 4);
  int* gcnt = (int*)alloc((size_t)NB * 4);
  float* h2 = h1;  // reuse (h2 is 4 MB, h1 no longer needed when agg2 runs)

  const int rows64 = (N_NODES + 63) / 64;        // 782
  const int eblk = (N_EDGES + 255) / 256;        // 6250
  const int nblk = (N_NODES + 255) / 256;        // 196
  const int nhblk = (N_NODES * NH + 255) / 256;  // 782

  // CSR build (graph identical both layers)
  hipMemsetAsync(cnt, 0, (size_t)N_NODES * 4, stream);
  hist_kernel<<<eblk, 256, 0, stream>>>(dst, cnt);
  scan_kernel<<<1, 1024, 0, stream>>>(cnt, row_ptr, N_NODES);
  copy_int_kernel<<<nblk, 256, 0, stream>>>(row_ptr, cursor, N_NODES);
  fill_kernel<<<eblk, 256, 0, stream>>>(src, dst, cursor, csr);

  // Layer 1
  gemm_heads_bf16<DIN, D1, NH, P1><<<dim3(rows64, 7), 256, 0, stream>>>(feat, W1, z1b, N_NODES);
  scores_kernel<D1, P1><<<nhblk, 256, 0, stream>>>(z1b, a1, ssrc, sdst);
  agg1_kernel<<<N_NODES, 256, 0, stream>>>(z1b, ssrc, sdst, row_ptr, csr, h1);

  // Layer 2
  gemm_heads_bf16<NH * D1, D2, NH, P2><<<dim3(rows64, 2), 256, 0, stream>>>(h1, W2, z2b, N_NODES);
  scores_kernel<D2, P2><<<nhblk, 256, 0, stream>>>(z2b, a2, ssrc, sdst);
  agg2_kernel<<<N_NODES, 256, 0, stream>>>(z2b, ssrc, sdst, row_ptr, csr, h2);

  // Readout
  hipMemsetAsync(hg, 0, (size_t)NB * D2 * 4, stream);
  hipMemsetAsync(gcnt, 0, (size_t)NB * 4, stream);
  pool_kernel<<<nblk, 256, 0, stream>>>(h2, gid, hg, gcnt);
  head_kernel<<<1, 256, 0, stream>>>(hg, gcnt, Wf1, bf1, Wf2, bf2, Wf3, bf3,
                                     gamma2, beta2, outp);
}

// Round 4
// 956.629 us; speedup vs baseline: 1.8445x; 1.0347x over previous
//
#include <hip/hip_runtime.h>
#include <hip/hip_bf16.h>
#include <math.h>

#define N_NODES 50000
#define N_EDGES 1600000
#define DIN 128
#define NH 4
#define D1 100
#define P1 128   // padded per-head width for z1 (bf16)
#define D2 20
#define P2 32    // padded per-head width for z2 (bf16)
#define NB 64
#define EPS_BN 1e-5f

typedef unsigned int uint;
typedef unsigned short ushort;

__device__ __forceinline__ void bf16x2_unpack(uint p, float& lo, float& hi) {
  lo = __uint_as_float(p << 16);
  hi = __uint_as_float(p & 0xffff0000u);
}

// ---------------------------------------------------------------------------
// fp32 GEMM -> bf16 head-padded output.
// ---------------------------------------------------------------------------
template <int K, int DOUT, int HEADS, int PAD>
__global__ __launch_bounds__(256) void gemm_heads_bf16(const float* __restrict__ A,
                                                       const float* __restrict__ W,
                                                       __hip_bfloat16* __restrict__ C,
                                                       int nrows) {
  constexpr int NC = HEADS * DOUT;
  constexpr int TM = 64, TN = 64, TK = 16;
  __shared__ __align__(16) float As[TK][TM + 4];
  __shared__ __align__(16) float Ws[TK][TN + 4];
  const int row0 = blockIdx.x * TM;
  const int col0 = blockIdx.y * TN;
  const int tid = threadIdx.x;
  const int tx = tid & 15, ty = tid >> 4;
  float acc[4][4] = {};
  for (int k0 = 0; k0 < K; k0 += TK) {
#pragma unroll
    for (int i = 0; i < 4; i++) {
      int r = (tid >> 4) + i * 16;
      int kk = tid & 15;
      int row = row0 + r;
      float v = 0.f;
      if (row < nrows) v = A[(size_t)row * K + k0 + kk];
      As[kk][r] = v;
    }
#pragma unroll
    for (int i = 0; i < 4; i++) {
      int kk = (tid >> 6) + i * 4;
      int cc = tid & 63;
      int c = col0 + cc;
      float v = 0.f;
      if (c < NC) {
        int h = c / DOUT, j = c % DOUT;
        v = W[((size_t)h * K + (k0 + kk)) * DOUT + j];
      }
      Ws[kk][cc] = v;
    }
    __syncthreads();
#pragma unroll
    for (int kk = 0; kk < TK; kk++) {
      float4 a4 = *reinterpret_cast<const float4*>(&As[kk][ty * 4]);
      float4 b4 = *reinterpret_cast<const float4*>(&Ws[kk][tx * 4]);
      acc[0][0] += a4.x * b4.x; acc[0][1] += a4.x * b4.y; acc[0][2] += a4.x * b4.z; acc[0][3] += a4.x * b4.w;
      acc[1][0] += a4.y * b4.x; acc[1][1] += a4.y * b4.y; acc[1][2] += a4.y * b4.z; acc[1][3] += a4.y * b4.w;
      acc[2][0] += a4.z * b4.x; acc[2][1] += a4.z * b4.y; acc[2][2] += a4.z * b4.z; acc[2][3] += a4.z * b4.w;
      acc[3][0] += a4.w * b4.x; acc[3][1] += a4.w * b4.y; acc[3][2] += a4.w * b4.z; acc[3][3] += a4.w * b4.w;
    }
    __syncthreads();
  }
#pragma unroll
  for (int i = 0; i < 4; i++) {
    int row = row0 + ty * 4 + i;
    if (row < nrows) {
#pragma unroll
      for (int j = 0; j < 4; j++) {
        int c = col0 + tx * 4 + j;
        if (c < NC) {
          int h = c / DOUT, cj = c % DOUT;
          C[(size_t)row * (HEADS * PAD) + h * PAD + cj] = __float2bfloat16(acc[i][j]);
        }
      }
    }
  }
}

// ---------------------------------------------------------------------------
// Attention scores from bf16 packed z. One thread per (node, head).
// ---------------------------------------------------------------------------
template <int DOUT, int PAD>
__global__ void scores_kernel(const __hip_bfloat16* __restrict__ z,
                              const float* __restrict__ a,
                              float* __restrict__ ssrc,
                              float* __restrict__ sdst) {
  int t = blockIdx.x * blockDim.x + threadIdx.x;
  if (t >= N_NODES * NH) return;
  int n = t >> 2;
  int h = t & 3;
  const uint* zr = reinterpret_cast<const uint*>(z) + (size_t)n * (NH * PAD / 2) + h * (PAD / 2);
  const float* as = a + h * 2 * DOUT;
  const float* ad = as + DOUT;
  float s1 = 0.f, s2 = 0.f;
  for (int j = 0; j < DOUT / 2; j++) {
    float lo, hi;
    bf16x2_unpack(zr[j], lo, hi);
    s1 += lo * as[2 * j] + hi * as[2 * j + 1];
    s2 += lo * ad[2 * j] + hi * ad[2 * j + 1];
  }
  ssrc[h * N_NODES + n] = s1;
  sdst[h * N_NODES + n] = s2;
}

// ---------------------------------------------------------------------------
// CSR build: histogram, 3-kernel hierarchical scan, cursor copy, fill
// ---------------------------------------------------------------------------
__global__ void hist_kernel(const int* __restrict__ dst, int* __restrict__ cnt) {
  int e = blockIdx.x * blockDim.x + threadIdx.x;
  if (e < N_EDGES) atomicAdd(&cnt[dst[e]], 1);
}

// per-block (512) exclusive scan + block totals
__global__ __launch_bounds__(512) void scan1_kernel(const int* __restrict__ cnt,
                                                    int* __restrict__ row_ptr,
                                                    int* __restrict__ btot, int n) {
  __shared__ int ws[8];
  int b = blockIdx.x, tid = threadIdx.x, lane = tid & 63, wv = tid >> 6;
  int i = b * 512 + tid;
  int v = (i < n) ? cnt[i] : 0;
  int orig = v;
  for (int off = 1; off < 64; off <<= 1) {
    int t = __shfl_up(v, off);
    if (lane >= off) v += t;
  }
  if (lane == 63) ws[wv] = v;
  __syncthreads();
  int wo = 0;
  for (int j = 0; j < wv; j++) wo += ws[j];
  if (i < n) row_ptr[i] = wo + v - orig;
  if (tid == 511) btot[b] = wo + v;
}

// exclusive scan of block totals (nb <= 128), writes grand total to row_ptr[n]
__global__ __launch_bounds__(128) void scan2_kernel(int* __restrict__ btot,
                                                    int* __restrict__ row_ptr_n, int nb) {
  __shared__ int ws2[2];
  int tid = threadIdx.x, lane = tid & 63, wv = tid >> 6;
  int v = (tid < nb) ? btot[tid] : 0;
  int orig = v;
  for (int off = 1; off < 64; off <<= 1) {
    int t = __shfl_up(v, off);
    if (lane >= off) v += t;
  }
  if (lane == 63) ws2[wv] = v;
  __syncthreads();
  int wo = (wv == 1) ? ws2[0] : 0;
  if (tid < nb) btot[tid] = wo + v - orig;
  if (tid == nb - 1) *row_ptr_n = wo + v;
}

__global__ __launch_bounds__(512) void scan3_kernel(int* __restrict__ row_ptr,
                                                    const int* __restrict__ btot, int n) {
  int i = blockIdx.x * 512 + threadIdx.x;
  if (i < n) row_ptr[i] += btot[blockIdx.x];
}

__global__ void copy_int_kernel(const int* __restrict__ a, int* __restrict__ b, int n) {
  int i = blockIdx.x * blockDim.x + threadIdx.x;
  if (i < n) b[i] = a[i];
}

__global__ void fill_kernel(const int* __restrict__ src, const int* __restrict__ dst,
                            int* __restrict__ cursor, int* __restrict__ csr_src,
                            int* __restrict__ csr_dst) {
  int e = blockIdx.x * blockDim.x + threadIdx.x;
  if (e < N_EDGES) {
    int d = dst[e];
    int p = atomicAdd(&cursor[d], 1);
    csr_src[p] = src[e];
    csr_dst[p] = d;
  }
}

// ---------------------------------------------------------------------------
// Edge-parallel softmax weights (no max subtraction; scores are O(1)):
// w[h][p] = exp(leaky(ssrc[h][src] + sdst[h][dst])), CSR order.
// ---------------------------------------------------------------------------
__global__ void weight_kernel(const float* __restrict__ ssrc,
                              const float* __restrict__ sdst,
                              const int* __restrict__ csr_src,
                              const int* __restrict__ csr_dst,
                              float* __restrict__ w) {
  int p = blockIdx.x * blockDim.x + threadIdx.x;
  if (p >= N_EDGES) return;
  int s = csr_src[p];
  int d = csr_dst[p];
#pragma unroll
  for (int h = 0; h < NH; h++) {
    float e = ssrc[h * N_NODES + s] + sdst[h * N_NODES + d];
    e = fmaxf(e, 0.01f * e);  // leaky_relu, slope 0.01
    w[(size_t)h * N_EDGES + p] = __expf(e);
  }
}

// ---------------------------------------------------------------------------
// GAT layer 1 aggregation. Block = dst, wave = head. Lanes 0..49 own a packed
// column pair. den via lane-parallel pass; main loop = w-broadcast + z gather.
// ---------------------------------------------------------------------------
__global__ __launch_bounds__(256) void agg1_kernel(const __hip_bfloat16* __restrict__ z,
                                                   const float* __restrict__ w,
                                                   const int* __restrict__ row_ptr,
                                                   const int* __restrict__ csr_src,
                                                   float* __restrict__ h1) {
  int d = blockIdx.x;
  int h = threadIdx.x >> 6, lane = threadIdx.x & 63;
  int beg = row_ptr[d], end = row_ptr[d + 1];
  int deg = end - beg;
  size_t obase = (size_t)d * (NH * D1) + h * D1;
  bool act = lane < D1 / 2;  // 50 lanes
  if (deg == 0) {
    if (act) *reinterpret_cast<float2*>(h1 + obase + 2 * lane) = make_float2(0.f, 0.f);
    return;
  }
  const float* wh = w + (size_t)h * N_EDGES;
  float den = 0.f;
  for (int i = lane; i < deg; i += 64) den += wh[beg + i];
#pragma unroll
  for (int off = 32; off > 0; off >>= 1) den += __shfl_xor(den, off);

  if (!act) return;
  const uint* zb = reinterpret_cast<const uint*>(z);
  const int hco = h * (P1 / 2) + lane;
  float aE0 = 0.f, aE1 = 0.f, aE2 = 0.f, aE3 = 0.f;
  float aO0 = 0.f, aO1 = 0.f, aO2 = 0.f, aO3 = 0.f;
  int i = 0;
  for (; i + 8 <= deg; i += 8) {
    int s0 = csr_src[beg + i + 0], s1 = csr_src[beg + i + 1];
    int s2 = csr_src[beg + i + 2], s3 = csr_src[beg + i + 3];
    int s4 = csr_src[beg + i + 4], s5 = csr_src[beg + i + 5];
    int s6 = csr_src[beg + i + 6], s7 = csr_src[beg + i + 7];
    float x0 = wh[beg + i + 0], x1 = wh[beg + i + 1];
    float x2 = wh[beg + i + 2], x3 = wh[beg + i + 3];
    float x4 = wh[beg + i + 4], x5 = wh[beg + i + 5];
    float x6 = wh[beg + i + 6], x7 = wh[beg + i + 7];
    uint p0 = zb[(size_t)s0 * (NH * P1 / 2) + hco];
    uint p1 = zb[(size_t)s1 * (NH * P1 / 2) + hco];
    uint p2 = zb[(size_t)s2 * (NH * P1 / 2) + hco];
    uint p3 = zb[(size_t)s3 * (NH * P1 / 2) + hco];
    uint p4 = zb[(size_t)s4 * (NH * P1 / 2) + hco];
    uint p5 = zb[(size_t)s5 * (NH * P1 / 2) + hco];
    uint p6 = zb[(size_t)s6 * (NH * P1 / 2) + hco];
    uint p7 = zb[(size_t)s7 * (NH * P1 / 2) + hco];
    float lo, hi;
    bf16x2_unpack(p0, lo, hi); aE0 += x0 * lo; aO0 += x0 * hi;
    bf16x2_unpack(p1, lo, hi); aE1 += x1 * lo; aO1 += x1 * hi;
    bf16x2_unpack(p2, lo, hi); aE2 += x2 * lo; aO2 += x2 * hi;
    bf16x2_unpack(p3, lo, hi); aE3 += x3 * lo; aO3 += x3 * hi;
    bf16x2_unpack(p4, lo, hi); aE0 += x4 * lo; aO0 += x4 * hi;
    bf16x2_unpack(p5, lo, hi); aE1 += x5 * lo; aO1 += x5 * hi;
    bf16x2_unpack(p6, lo, hi); aE2 += x6 * lo; aO2 += x6 * hi;
    bf16x2_unpack(p7, lo, hi); aE3 += x7 * lo; aO3 += x7 * hi;
  }
  for (; i < deg; i++) {
    int s = csr_src[beg + i];
    float x = wh[beg + i];
    uint p = zb[(size_t)s * (NH * P1 / 2) + hco];
    float lo, hi;
    bf16x2_unpack(p, lo, hi);
    aE0 += x * lo; aO0 += x * hi;
  }
  float inv = 1.0f / den;
  float vE = ((aE0 + aE1) + (aE2 + aE3)) * inv;
  float vO = ((aO0 + aO1) + (aO2 + aO3)) * inv;
  float2 o;
  o.x = vE > 0.f ? vE : 0.f;
  o.y = vO > 0.f ? vO : 0.f;
  *reinterpret_cast<float2*>(h1 + obase + 2 * lane) = o;
}

// ---------------------------------------------------------------------------
// GAT layer 2 aggregation + head-mean + relu. Wave = head.
// 6 edge-groups x 10 lanes (col pair each), 2x unroll.
// ---------------------------------------------------------------------------
__global__ __launch_bounds__(256) void agg2_kernel(const __hip_bfloat16* __restrict__ z,
                                                   const float* __restrict__ w,
                                                   const int* __restrict__ row_ptr,
                                                   const int* __restrict__ csr_src,
                                                   float* __restrict__ h2) {
  __shared__ float hbuf[NH][D2];
  int d = blockIdx.x;
  int h = threadIdx.x >> 6, lane = threadIdx.x & 63;
  int beg = row_ptr[d], end = row_ptr[d + 1];
  int deg = end - beg;
  int g = lane / 10;
  int j = lane - g * 10;
  if (deg > 0) {
    const float* wh = w + (size_t)h * N_EDGES;
    float den = 0.f;
    for (int i = lane; i < deg; i += 64) den += wh[beg + i];
#pragma unroll
    for (int off = 32; off > 0; off >>= 1) den += __shfl_xor(den, off);

    const uint* zb = reinterpret_cast<const uint*>(z);
    const int hco = h * (P2 / 2) + j;
    float aE = 0.f, aO = 0.f;
    if (g < 6) {
      int i = g;
      for (; i + 6 < deg; i += 12) {
        int s0 = csr_src[beg + i];
        int s1 = csr_src[beg + i + 6];
        float x0 = wh[beg + i];
        float x1 = wh[beg + i + 6];
        uint p0 = zb[(size_t)s0 * (NH * P2 / 2) + hco];
        uint p1 = zb[(size_t)s1 * (NH * P2 / 2) + hco];
        float lo, hi;
        bf16x2_unpack(p0, lo, hi); aE += x0 * lo; aO += x0 * hi;
        bf16x2_unpack(p1, lo, hi); aE += x1 * lo; aO += x1 * hi;
      }
      if (i < deg) {
        int s = csr_src[beg + i];
        float x = wh[beg + i];
        uint p = zb[(size_t)s * (NH * P2 / 2) + hco];
        float lo, hi;
        bf16x2_unpack(p, lo, hi);
        aE += x * lo; aO += x * hi;
      }
    }
    float tE = aE, tO = aO;
#pragma unroll
    for (int k = 1; k < 6; k++) {
      tE += __shfl(aE, lane + 10 * k);
      tO += __shfl(aO, lane + 10 * k);
    }
    if (lane < 10) {
      float invd = 1.0f / den;
      hbuf[h][2 * j] = tE * invd;
      hbuf[h][2 * j + 1] = tO * invd;
    }
  } else {
    if (lane < 10) {
      hbuf[h][2 * j] = 0.f;
      hbuf[h][2 * j + 1] = 0.f;
    }
  }
  __syncthreads();
  if (threadIdx.x < D2) {
    int c = threadIdx.x;
    float m = 0.25f * (hbuf[0][c] + hbuf[1][c] + hbuf[2][c] + hbuf[3][c]);
    h2[(size_t)d * D2 + c] = m > 0.f ? m : 0.f;
  }
}

// ---------------------------------------------------------------------------
// Graph mean-pool (stage 1): wave-level pre-reduction (graph_id is sorted).
// ---------------------------------------------------------------------------
__global__ __launch_bounds__(256) void pool_kernel(const float* __restrict__ h2,
                                                   const int* __restrict__ gid,
                                                   float* __restrict__ hg,
                                                   int* __restrict__ gcnt) {
  int wave = threadIdx.x >> 6, lane = threadIdx.x & 63;
  int n = (blockIdx.x * 4 + wave) * 64 + lane;
  bool valid = n < N_NODES;
  int g = gid[valid ? n : (N_NODES - 1)];
  int g0 = __shfl(g, 0), g63 = __shfl(g, 63);
  unsigned long long mask = __ballot(valid);
  if (g0 == g63) {
    if (lane == 0) atomicAdd(&gcnt[g0], (int)__popcll(mask));
#pragma unroll
    for (int c = 0; c < D2; c++) {
      float v = valid ? h2[(size_t)n * D2 + c] : 0.f;
#pragma unroll
      for (int off = 32; off > 0; off >>= 1) v += __shfl_xor(v, off);
      if (lane == 0) atomicAdd(&hg[g0 * D2 + c], v);
    }
  } else if (valid) {
    atomicAdd(&gcnt[g], 1);
    for (int c = 0; c < D2; c++) atomicAdd(&hg[g * D2 + c], h2[(size_t)n * D2 + c]);
  }
}

// ---------------------------------------------------------------------------
// Readout MLP + BatchNorm + final projection in one block.
// ---------------------------------------------------------------------------
__global__ __launch_bounds__(256) void head_kernel(const float* __restrict__ hg,
                                                   const int* __restrict__ gcnt,
                                                   const float* __restrict__ Wf1,
                                                   const float* __restrict__ bf1,
                                                   const float* __restrict__ Wf2,
                                                   const float* __restrict__ bf2,
                                                   const float* __restrict__ Wf3,
                                                   const float* __restrict__ bf3,
                                                   const float* __restrict__ gamma,
                                                   const float* __restrict__ beta,
                                                   float* __restrict__ out) {
  __shared__ float X[NB][D2];
  __shared__ float T1[NB][128];
  __shared__ float T2[NB][32];
  __shared__ float scale_s[32], shift_s[32];
  int tid = threadIdx.x;
  for (int i = tid; i < NB * D2; i += 256) {
    int r = i / D2, c = i % D2;
    X[r][c] = hg[i] / (float)gcnt[r];
  }
  __syncthreads();
  for (int i = tid; i < NB * 128; i += 256) {
    int r = i >> 7, c = i & 127;
    float s = bf1[c];
#pragma unroll
    for (int k = 0; k < D2; k++) s += X[r][k] * Wf1[k * 128 + c];
    T1[r][c] = s > 0.f ? s : 0.f;
  }
  __syncthreads();
  for (int i = tid; i < NB * 32; i += 256) {
    int r = i >> 5, c = i & 31;
    float s = bf2[c];
#pragma unroll
    for (int k = 0; k < 128; k++) s += T1[r][k] * Wf2[k * 32 + c];
    T2[r][c] = s;
  }
  __syncthreads();
  if (tid < 32) {
    float mu = 0.f;
    for (int r = 0; r < NB; r++) mu += T2[r][tid];
    mu *= (1.f / NB);
    float var = 0.f;
    for (int r = 0; r < NB; r++) {
      float dv = T2[r][tid] - mu;
      var += dv * dv;
    }
    var *= (1.f / NB);
    float sc = gamma[tid] * rsqrtf(var + EPS_BN);
    scale_s[tid] = sc;
    shift_s[tid] = beta[tid] - mu * sc;
  }
  __syncthreads();
  if (tid < NB) {
    float s = bf3[0];
#pragma unroll
    for (int c = 0; c < 32; c++) {
      float y = scale_s[c] * T2[tid][c] + shift_s[c];
      y = y > 0.f ? y : 0.f;
      s += y * Wf3[c];
    }
    out[tid] = s;
  }
}

// ---------------------------------------------------------------------------

extern "C" void kernel_launch(void* const* d_in, const int* in_sizes, int n_in,
                              void* d_out, int out_size, void* d_ws, size_t ws_size,
                              hipStream_t stream) {
  const float* feat = (const float*)d_in[0];
  const int* src = (const int*)d_in[1];
  const int* dst = (const int*)d_in[2];
  const int* gid = (const int*)d_in[3];
  const float* W1 = (const float*)d_in[4];
  const float* a1 = (const float*)d_in[5];
  const float* W2 = (const float*)d_in[6];
  const float* a2 = (const float*)d_in[7];
  const float* Wf1 = (const float*)d_in[8];
  const float* bf1 = (const float*)d_in[9];
  const float* Wf2 = (const float*)d_in[10];
  const float* bf2 = (const float*)d_in[11];
  const float* Wf3 = (const float*)d_in[12];
  const float* bf3 = (const float*)d_in[13];
  const float* gamma2 = (const float*)d_in[14];
  const float* beta2 = (const float*)d_in[15];
  float* outp = (float*)d_out;

  char* p = (char*)d_ws;
  auto alloc = [&](size_t bytes) {
    void* q = (void*)p;
    p += (bytes + 255) & ~(size_t)255;
    return q;
  };
  __hip_bfloat16* z1b = (__hip_bfloat16*)alloc((size_t)N_NODES * NH * P1 * 2);  // 51.2 MB
  __hip_bfloat16* z2b = (__hip_bfloat16*)alloc((size_t)N_NODES * NH * P2 * 2);  // 12.8 MB
  float* h1 = (float*)alloc((size_t)N_NODES * NH * D1 * 4);                      // 80 MB
  float* ssrc = (float*)alloc((size_t)NH * N_NODES * 4);
  float* sdst = (float*)alloc((size_t)NH * N_NODES * 4);
  float* wbuf = (float*)alloc((size_t)NH * N_EDGES * 4);                         // 25.6 MB (reused L1/L2)
  int* cnt = (int*)alloc((size_t)N_NODES * 4);
  int* row_ptr = (int*)alloc((size_t)(N_NODES + 1) * 4);
  int* cursor = (int*)alloc((size_t)N_NODES * 4);
  int* csr = (int*)alloc((size_t)N_EDGES * 4);
  int* csr_d = (int*)alloc((size_t)N_EDGES * 4);
  int* btot = (int*)alloc((size_t)128 * 4);
  float* hg = (float*)alloc((size_t)NB * D2 * 4);
  int* gcnt = (int*)alloc((size_t)NB * 4);
  float* h2 = h1;  // reuse

  const int rows64 = (N_NODES + 63) / 64;        // 782
  const int eblk = (N_EDGES + 255) / 256;        // 6250
  const int nblk = (N_NODES + 255) / 256;        // 196
  const int nhblk = (N_NODES * NH + 255) / 256;  // 782
  const int sblk = (N_NODES + 511) / 512;        // 98

  // CSR build
  hipMemsetAsync(cnt, 0, (size_t)N_NODES * 4, stream);
  hist_kernel<<<eblk, 256, 0, stream>>>(dst, cnt);
  scan1_kernel<<<sblk, 512, 0, stream>>>(cnt, row_ptr, btot, N_NODES);
  scan2_kernel<<<1, 128, 0, stream>>>(btot, row_ptr + N_NODES, sblk);
  scan3_kernel<<<sblk, 512, 0, stream>>>(row_ptr, btot, N_NODES);
  copy_int_kernel<<<nblk, 256, 0, stream>>>(row_ptr, cursor, N_NODES);
  fill_kernel<<<eblk, 256, 0, stream>>>(src, dst, cursor, csr, csr_d);

  // Layer 1
  gemm_heads_bf16<DIN, D1, NH, P1><<<dim3(rows64, 7), 256, 0, stream>>>(feat, W1, z1b, N_NODES);
  scores_kernel<D1, P1><<<nhblk, 256, 0, stream>>>(z1b, a1, ssrc, sdst);
  weight_kernel<<<eblk, 256, 0, stream>>>(ssrc, sdst, csr, csr_d, wbuf);
  agg1_kernel<<<N_NODES, 256, 0, stream>>>(z1b, wbuf, row_ptr, csr, h1);

  // Layer 2
  gemm_heads_bf16<NH * D1, D2, NH, P2><<<dim3(rows64, 2), 256, 0, stream>>>(h1, W2, z2b, N_NODES);
  scores_kernel<D2, P2><<<nhblk, 256, 0, stream>>>(z2b, a2, ssrc, sdst);
  weight_kernel<<<eblk, 256, 0, stream>>>(ssrc, sdst, csr, csr_d, wbuf);
  agg2_kernel<<<N_NODES, 256, 0, stream>>>(z2b, wbuf, row_ptr, csr, h2);

  // Readout
  hipMemsetAsync(hg, 0, (size_t)NB * D2 * 4, stream);
  hipMemsetAsync(gcnt, 0, (size_t)NB * 4, stream);
  pool_kernel<<<nblk, 256, 0, stream>>>(h2, gid, hg, gcnt);
  head_kernel<<<1, 256, 0, stream>>>(hg, gcnt, Wf1, bf1, Wf2, bf2, Wf3, bf3,
                                     gamma2, beta2, outp);
}